// Round 8
// baseline (859.037 us; speedup 1.0000x reference)
//
#include <hip/hip_runtime.h>
#include <cstdint>
#include <cstddef>

typedef uint16_t u16;
typedef __bf16 bf16x8 __attribute__((ext_vector_type(8)));
typedef __bf16 bf16x4 __attribute__((ext_vector_type(4)));
typedef short s16x4 __attribute__((ext_vector_type(4)));
typedef float f32x4 __attribute__((ext_vector_type(4)));
typedef unsigned short us4 __attribute__((ext_vector_type(4)));

#define NTOK 131072          // B*N = 8*16384
#define CDIM 128
#define MFMA __builtin_amdgcn_mfma_f32_16x16x32_bf16

__device__ __forceinline__ u16 f2b(float f) {
    unsigned int x = __builtin_bit_cast(unsigned int, f);
    unsigned int r = (x + 0x7fffu + ((x >> 16) & 1u)) >> 16;
    return (u16)r;
}

__device__ __forceinline__ us4 pack_bn4(float4 v, const float* sc, const float* sh, int c) {
    us4 o;
    o.x = f2b(v.x * sc[c] + sh[c]);
    o.y = f2b(v.y * sc[c + 1] + sh[c + 1]);
    o.z = f2b(v.z * sc[c + 2] + sh[c + 2]);
    o.w = f2b(v.w * sc[c + 3] + sh[c + 3]);
    return o;
}

__device__ __forceinline__ s16x4 cvt4(f32x4 v) {
    bf16x4 b;
    b[0] = (__bf16)v[0]; b[1] = (__bf16)v[1];
    b[2] = (__bf16)v[2]; b[3] = (__bf16)v[3];
    return __builtin_bit_cast(s16x4, b);
}

// 16x16x16 bf16 MFMA (K=16): A/B = s16x4 (4 bf16), C = f32x4.
__device__ __forceinline__ f32x4 mfma16(s16x4 a, s16x4 b, f32x4 c) {
#if __has_builtin(__builtin_amdgcn_mfma_f32_16x16x16bf16_1k)
    return __builtin_amdgcn_mfma_f32_16x16x16bf16_1k(a, b, c, 0, 0, 0);
#else
    asm volatile("s_nop 3\n\tv_mfma_f32_16x16x16_bf16 %0, %1, %2, %0\n\ts_nop 7"
                 : "+v"(c) : "v"(a), "v"(b));
    return c;
#endif
}

// ---------------- initial BN stats on x_in (vectorized, 8-way spread atomics)
__global__ __launch_bounds__(256) void bn_init(const float* __restrict__ x,
                                               float* __restrict__ acc) {
    int tid = threadIdx.x;
    int c4 = tid & 31;
    int ro = tid >> 5;
    float4 s = {0.f, 0.f, 0.f, 0.f}, s2 = {0.f, 0.f, 0.f, 0.f};
    size_t base = ((size_t)blockIdx.x * 128 + ro) * 128 + c4 * 4;
#pragma unroll
    for (int it = 0; it < 16; ++it) {
        float4 v = *(const float4*)(x + base + (size_t)it * 1024);
        s.x += v.x; s.y += v.y; s.z += v.z; s.w += v.w;
        s2.x += v.x * v.x; s2.y += v.y * v.y; s2.z += v.z * v.z; s2.w += v.w * v.w;
    }
    __shared__ float4 a1[256], a2[256];
    a1[tid] = s; a2[tid] = s2;
    __syncthreads();
    if (tid < 128) {
        int col4 = tid >> 2, comp = tid & 3;
        float t1 = 0.f, t2 = 0.f;
#pragma unroll
        for (int r = 0; r < 8; ++r) {
            t1 += a1[r * 32 + col4][comp];
            t2 += a2[r * 32 + col4][comp];
        }
        float* st = acc + (blockIdx.x & 7) * 256;
        atomicAdd(st + tid, t1);
        atomicAdd(st + 128 + tid, t2);
    }
}

// ---------------- finalize: sum 8 copies, produce scale/shift
__global__ void bn_finalize(const float* __restrict__ acc, const float* __restrict__ g,
                            const float* __restrict__ b, float* __restrict__ scsh) {
    int c = threadIdx.x;  // 128 threads
    const float invn = 1.0f / (float)NTOK;
    float s = 0.f, q = 0.f;
#pragma unroll
    for (int k = 0; k < 8; ++k) {
        s += acc[k * 256 + c];
        q += acc[k * 256 + 128 + c];
    }
    float mean = s * invn;
    float var = q * invn - mean * mean;
    float sc = g[c] * rsqrtf(var + 1e-5f);
    scsh[c] = sc;
    scsh[128 + c] = b[c] - mean * sc;
}

// ---------------- weight transpose+convert: wt[n*K+k] = bf16(w[k*N+n])
__global__ __launch_bounds__(256) void wtrans(const float* __restrict__ w, u16* __restrict__ wt,
                                              int K, int N) {
    int t = blockIdx.x * 256 + threadIdx.x;
    if (t >= K * N) return;
    int n = t % N, k = t / N;
    wt[(size_t)n * K + k] = f2b(w[t]);
}

// ---------------- fused attention block: gather+BN1+QKV+attn+proj+resid+BN2stats
// One 64-token window per block; wave = head. QK^T/softmax/PV fully in registers.
__global__ __launch_bounds__(256, 3) void attn_fused(
    const float* __restrict__ xsrc, float* __restrict__ xdst,
    const int* __restrict__ ip, const float* __restrict__ scsh,
    const u16* __restrict__ wqt, const u16* __restrict__ wpt,
    float* __restrict__ stat)
{
    __shared__ u16 buf[64 * 136];      // [tok][136]: h (BN'd, bf16), later O
    __shared__ float sc[128], sh[128];
    __shared__ int ipl[64];

    int tid = threadIdx.x;
    int lane = tid & 63, wv = tid >> 6;
    int l15 = lane & 15, hi = lane >> 4;
    int b = blockIdx.x >> 8;

    if (tid < 128) { sc[tid] = scsh[tid]; sh[tid] = scsh[128 + tid]; }
    if (tid < 64) ipl[tid] = ip[blockIdx.x * 64 + tid];
    __syncthreads();

    // ---- stage h = BN1(x[ip rows]) -> buf rows (272B stride)
    int c4 = tid & 31;
#pragma unroll
    for (int p = 0; p < 8; ++p) {
        int row = p * 8 + (tid >> 5);
        int grow = (b << 14) + ipl[row];
        float4 v = *(const float4*)(xsrc + (size_t)grow * 128 + c4 * 4);
        us4 o = pack_bn4(v, sc, sh, c4 * 4);
        *(us4*)(buf + row * 136 + c4 * 4) = o;
    }
    __syncthreads();

    // ---- QKV GEMMs. Q',K' swapped: [d][tok]; V normal: [tok][dv]. head = wv.
    f32x4 aQ[2][4], aK[2][4], aV[4][2];
#pragma unroll
    for (int i = 0; i < 2; ++i)
#pragma unroll
        for (int j = 0; j < 4; ++j) { aQ[i][j] = (f32x4){0,0,0,0}; aK[i][j] = (f32x4){0,0,0,0}; }
#pragma unroll
    for (int i = 0; i < 4; ++i)
#pragma unroll
        for (int j = 0; j < 2; ++j) aV[i][j] = (f32x4){0,0,0,0};

#pragma unroll
    for (int ks = 0; ks < 4; ++ks) {
        bf16x8 hf[4];
#pragma unroll
        for (int t = 0; t < 4; ++t)
            hf[t] = *(const bf16x8*)(buf + (t * 16 + l15) * 136 + ks * 32 + hi * 8);
        bf16x8 qf[2], kf[2], vf[2];
#pragma unroll
        for (int md = 0; md < 2; ++md) {
            int rq = wv * 32 + md * 16 + l15;
            qf[md] = *(const bf16x8*)(wqt + (size_t)rq * 128 + ks * 32 + hi * 8);
            kf[md] = *(const bf16x8*)(wqt + (size_t)(128 + rq) * 128 + ks * 32 + hi * 8);
            vf[md] = *(const bf16x8*)(wqt + (size_t)(256 + rq) * 128 + ks * 32 + hi * 8);
        }
#pragma unroll
        for (int md = 0; md < 2; ++md)
#pragma unroll
            for (int nt = 0; nt < 4; ++nt) {
                aQ[md][nt] = MFMA(qf[md], hf[nt], aQ[md][nt], 0, 0, 0);
                aK[md][nt] = MFMA(kf[md], hf[nt], aK[md][nt], 0, 0, 0);
            }
#pragma unroll
        for (int mt = 0; mt < 4; ++mt)
#pragma unroll
            for (int nd = 0; nd < 2; ++nd)
                aV[mt][nd] = MFMA(hf[mt], vf[nd], aV[mt][nd], 0, 0, 0);
    }

    // ---- convert to bf16 fragments (scale folded into Q)
    const float SCALE = 0.17677669529663687f;  // 1/sqrt(32)
    s16x4 qc[2][4], kc[2][4], vc[4][2];
#pragma unroll
    for (int md = 0; md < 2; ++md)
#pragma unroll
        for (int nt = 0; nt < 4; ++nt) {
            qc[md][nt] = cvt4(aQ[md][nt] * SCALE);
            kc[md][nt] = cvt4(aK[md][nt]);
        }
#pragma unroll
    for (int mt = 0; mt < 4; ++mt)
#pragma unroll
        for (int nd = 0; nd < 2; ++nd)
            vc[mt][nd] = cvt4(aV[mt][nd]);

    // ---- S' = K·Q^T : [k_tok][q], lane holds q=l15 col, 16 k per (mt,hi)
    f32x4 s[4][4];
#pragma unroll
    for (int i = 0; i < 4; ++i)
#pragma unroll
        for (int j = 0; j < 4; ++j) s[i][j] = (f32x4){0,0,0,0};
#pragma unroll
    for (int kt = 0; kt < 2; ++kt)
#pragma unroll
        for (int mt = 0; mt < 4; ++mt)
#pragma unroll
            for (int nt = 0; nt < 4; ++nt)
                s[mt][nt] = mfma16(kc[kt][mt], qc[kt][nt], s[mt][nt]);

    // ---- softmax over k (in-lane 16 + shfl over hi groups)
    float inv[4];
#pragma unroll
    for (int nt = 0; nt < 4; ++nt) {
        float m = -1e30f;
#pragma unroll
        for (int mt = 0; mt < 4; ++mt)
#pragma unroll
            for (int r = 0; r < 4; ++r) m = fmaxf(m, s[mt][nt][r]);
        m = fmaxf(m, __shfl_xor(m, 16));
        m = fmaxf(m, __shfl_xor(m, 32));
        float sum = 0.f;
#pragma unroll
        for (int mt = 0; mt < 4; ++mt) {
            f32x4 e;
#pragma unroll
            for (int r = 0; r < 4; ++r) e[r] = __expf(s[mt][nt][r] - m);
            sum += e[0] + e[1] + e[2] + e[3];
            s[mt][nt] = e;
        }
        sum += __shfl_xor(sum, 16);
        sum += __shfl_xor(sum, 32);
        inv[nt] = 1.0f / sum;
    }
    s16x4 pc[4][4];
#pragma unroll
    for (int mt = 0; mt < 4; ++mt)
#pragma unroll
        for (int nt = 0; nt < 4; ++nt) pc[mt][nt] = cvt4(s[mt][nt]);

    // ---- O^T = V^T·P : [dv][q]
    f32x4 o[2][4];
#pragma unroll
    for (int i = 0; i < 2; ++i)
#pragma unroll
        for (int j = 0; j < 4; ++j) o[i][j] = (f32x4){0,0,0,0};
#pragma unroll
    for (int kt = 0; kt < 4; ++kt)
#pragma unroll
        for (int md = 0; md < 2; ++md)
#pragma unroll
            for (int nt = 0; nt < 4; ++nt)
                o[md][nt] = mfma16(vc[kt][md], pc[kt][nt], o[md][nt]);
#pragma unroll
    for (int md = 0; md < 2; ++md)
#pragma unroll
        for (int nt = 0; nt < 4; ++nt) o[md][nt] *= inv[nt];

    // ---- write O (bf16) to buf[tok][dv] (h is dead; all QKV reads done)
    __syncthreads();
#pragma unroll
    for (int md = 0; md < 2; ++md)
#pragma unroll
        for (int nt = 0; nt < 4; ++nt) {
            s16x4 w = cvt4(o[md][nt]);
            *(s16x4*)(buf + (nt * 16 + l15) * 136 + wv * 32 + md * 16 + hi * 4) = w;
        }
    __syncthreads();

    // ---- proj: out 64 x 32 per wave + residual + BN2 stats
    f32x4 p[4][2];
#pragma unroll
    for (int i = 0; i < 4; ++i)
#pragma unroll
        for (int j = 0; j < 2; ++j) p[i][j] = (f32x4){0,0,0,0};
#pragma unroll
    for (int ks = 0; ks < 4; ++ks) {
        bf16x8 af[4];
#pragma unroll
        for (int t = 0; t < 4; ++t)
            af[t] = *(const bf16x8*)(buf + (t * 16 + l15) * 136 + ks * 32 + hi * 8);
#pragma unroll
        for (int nt = 0; nt < 2; ++nt) {
            bf16x8 bf = *(const bf16x8*)(wpt + (size_t)(wv * 32 + nt * 16 + l15) * 128 + ks * 32 + hi * 8);
#pragma unroll
            for (int t = 0; t < 4; ++t)
                p[t][nt] = MFMA(af[t], bf, p[t][nt], 0, 0, 0);
        }
    }
    float cs[2] = {0.f, 0.f}, cq[2] = {0.f, 0.f};
#pragma unroll
    for (int t = 0; t < 4; ++t)
#pragma unroll
        for (int r = 0; r < 4; ++r) {
            int tok = t * 16 + hi * 4 + r;
            size_t grow = (size_t)((b << 14) + ipl[tok]) * 128;
#pragma unroll
            for (int nt = 0; nt < 2; ++nt) {
                int col = wv * 32 + nt * 16 + l15;
                float v = p[t][nt][r] + xsrc[grow + col];
                xdst[grow + col] = v;
                cs[nt] += v; cq[nt] += v * v;
            }
        }
#pragma unroll
    for (int nt = 0; nt < 2; ++nt) {
        cs[nt] += __shfl_xor(cs[nt], 16); cs[nt] += __shfl_xor(cs[nt], 32);
        cq[nt] += __shfl_xor(cq[nt], 16); cq[nt] += __shfl_xor(cq[nt], 32);
    }
    if (lane < 16) {
        float* st = stat + (blockIdx.x & 7) * 256;
#pragma unroll
        for (int nt = 0; nt < 2; ++nt) {
            int col = wv * 32 + nt * 16 + l15;
            atomicAdd(st + col, cs[nt]);
            atomicAdd(st + 128 + col, cq[nt]);
        }
    }
}

// ---------------- fused MLP: BN2+fc1+relu+fc2+resid (+next BN1 stats)
// Wave owns 32 tokens. fc1 swapped (C'[h][tok]); its accumulator IS the fc2
// A-fragment for 16x16x16 MFMA (tok=l15, k=h=hi*4+r) -> no transpose, no LDS,
// no barriers. fc2 accumulated over 32 k-chunks via mfma16.
__global__ __launch_bounds__(256, 3) void mlp_fused(
    const float* __restrict__ xsrc, float* __restrict__ xdst,
    const float* __restrict__ scsh,
    const u16* __restrict__ w1t, const u16* __restrict__ w2t,
    float* __restrict__ stat)
{
    __shared__ float sc[128], sh[128];
    int tid = threadIdx.x, lane = tid & 63, wv = tid >> 6;
    int l15 = lane & 15, hi = lane >> 4;
    int tok0 = blockIdx.x * 128 + wv * 32;
    if (tid < 128) { sc[tid] = scsh[tid]; sh[tid] = scsh[128 + tid]; }
    __syncthreads();

    // ---- h B-frags straight from global with BN (lane = token l15), 2 subtiles
    bf16x8 hf[2][4];
#pragma unroll
    for (int mt = 0; mt < 2; ++mt)
#pragma unroll
        for (int ks = 0; ks < 4; ++ks) {
            const float* xr = xsrc + (size_t)(tok0 + mt * 16 + l15) * 128 + ks * 32 + hi * 8;
            float4 a = *(const float4*)xr;
            float4 bq = *(const float4*)(xr + 4);
            int c0 = ks * 32 + hi * 8;
            float4 s0 = *(const float4*)&sc[c0], s1 = *(const float4*)&sc[c0 + 4];
            float4 h0 = *(const float4*)&sh[c0], h1 = *(const float4*)&sh[c0 + 4];
            bf16x8 h;
            h[0] = (__bf16)(a.x * s0.x + h0.x); h[1] = (__bf16)(a.y * s0.y + h0.y);
            h[2] = (__bf16)(a.z * s0.z + h0.z); h[3] = (__bf16)(a.w * s0.w + h0.w);
            h[4] = (__bf16)(bq.x * s1.x + h1.x); h[5] = (__bf16)(bq.y * s1.y + h1.y);
            h[6] = (__bf16)(bq.z * s1.z + h1.z); h[7] = (__bf16)(bq.w * s1.w + h1.w);
            hf[mt][ks] = h;
        }

    f32x4 a2[8][2];
#pragma unroll
    for (int n = 0; n < 8; ++n) { a2[n][0] = (f32x4){0,0,0,0}; a2[n][1] = (f32x4){0,0,0,0}; }

#pragma unroll
    for (int ch = 0; ch < 4; ++ch) {
        // fc1 swapped: per 16-h tile, 4x K=32 MFMA; relu+cvt -> fc2 A-frag
        s16x4 pc[8][2];
#pragma unroll
        for (int ht = 0; ht < 8; ++ht) {
            f32x4 a1[2] = {(f32x4){0,0,0,0}, (f32x4){0,0,0,0}};
#pragma unroll
            for (int ks = 0; ks < 4; ++ks) {
                bf16x8 wf = *(const bf16x8*)(w1t + (size_t)(ch * 128 + ht * 16 + l15) * 128 + ks * 32 + hi * 8);
                a1[0] = MFMA(wf, hf[0][ks], a1[0], 0, 0, 0);
                a1[1] = MFMA(wf, hf[1][ks], a1[1], 0, 0, 0);
            }
#pragma unroll
            for (int mt = 0; mt < 2; ++mt) {
                f32x4 v = a1[mt];
#pragma unroll
                for (int r = 0; r < 4; ++r) v[r] = fmaxf(v[r], 0.f);
                pc[ht][mt] = cvt4(v);
            }
        }
        // fc2: k-chunks of 16 via mfma16; B-frag = w2t 8B load
#pragma unroll
        for (int ht = 0; ht < 8; ++ht)
#pragma unroll
            for (int nt = 0; nt < 8; ++nt) {
                s16x4 wb = *(const s16x4*)(w2t + (size_t)(nt * 16 + l15) * 512 + ch * 128 + ht * 16 + hi * 4);
                a2[nt][0] = mfma16(pc[ht][0], wb, a2[nt][0]);
                a2[nt][1] = mfma16(pc[ht][1], wb, a2[nt][1]);
            }
    }

    // ---- epilogue: residual + write + (optional) next-BN1 stats
    float cs[8], cq[8];
#pragma unroll
    for (int n = 0; n < 8; ++n) { cs[n] = 0.f; cq[n] = 0.f; }
#pragma unroll
    for (int mt = 0; mt < 2; ++mt)
#pragma unroll
        for (int r = 0; r < 4; ++r) {
            size_t row = (size_t)(tok0 + mt * 16 + hi * 4 + r) * 128;
#pragma unroll
            for (int nt = 0; nt < 8; ++nt) {
                int col = nt * 16 + l15;
                float v = a2[nt][mt][r] + xsrc[row + col];
                xdst[row + col] = v;
                cs[nt] += v; cq[nt] += v * v;
            }
        }
    if (stat) {
#pragma unroll
        for (int nt = 0; nt < 8; ++nt) {
            cs[nt] += __shfl_xor(cs[nt], 16); cs[nt] += __shfl_xor(cs[nt], 32);
            cq[nt] += __shfl_xor(cq[nt], 16); cq[nt] += __shfl_xor(cq[nt], 32);
        }
        if (lane < 16) {
            float* st = stat + (blockIdx.x & 7) * 256;
#pragma unroll
            for (int nt = 0; nt < 8; ++nt) {
                int col = nt * 16 + l15;
                atomicAdd(st + col, cs[nt]);
                atomicAdd(st + 128 + col, cq[nt]);
            }
        }
    }
}

extern "C" void kernel_launch(void* const* d_in, const int* in_sizes, int n_in,
                              void* d_out, int out_size, void* d_ws, size_t ws_size,
                              hipStream_t stream) {
    const float* x_in = (const float*)d_in[0];
    const float* z_in = (const float*)d_in[1];
    const int* ip1 = (const int*)d_in[2];
    const int* ip2 = (const int*)d_in[3];
    const float* qkv_w = (const float*)d_in[4];
    const float* proj_w = (const float*)d_in[5];
    const float* fc1_w = (const float*)d_in[6];
    const float* fc2_w = (const float*)d_in[7];
    const float* n1g = (const float*)d_in[8];
    const float* n1b = (const float*)d_in[9];
    const float* n2g = (const float*)d_in[10];
    const float* n2b = (const float*)d_in[11];

    char* ws = (char*)d_ws;
    float* xbuf = (float*)(ws + 0);                 // 67,108,864 B
    u16* wtb = (u16*)(ws + 67108864);               // 786,432 B
    float* stats = (float*)(ws + 67895296);         // S0..S3: 4 x 2048 floats (8 copies each)
    float* scsh = stats + 4 * 2048;                 // 256 floats

    float* out_x = (float*)d_out;
    float* out_z = out_x + (size_t)NTOK * CDIM;

    hipMemsetAsync(stats, 0, 4 * 2048 * sizeof(float), stream);
    hipMemcpyAsync(out_z, z_in, (size_t)NTOK * 3 * sizeof(float),
                   hipMemcpyDeviceToDevice, stream);

    for (int i = 0; i < 2; ++i) {
        wtrans<<<(128 * 384 + 255) / 256, 256, 0, stream>>>(qkv_w + (size_t)i * 128 * 384,
                                                            wtb + i * 49152, 128, 384);
        wtrans<<<(128 * 128 + 255) / 256, 256, 0, stream>>>(proj_w + (size_t)i * 128 * 128,
                                                            wtb + 98304 + i * 16384, 128, 128);
        wtrans<<<(128 * 512 + 255) / 256, 256, 0, stream>>>(fc1_w + (size_t)i * 128 * 512,
                                                            wtb + 131072 + i * 65536, 128, 512);
        wtrans<<<(512 * 128 + 255) / 256, 256, 0, stream>>>(fc2_w + (size_t)i * 512 * 128,
                                                            wtb + 262144 + i * 65536, 512, 128);
    }

    bn_init<<<1024, 256, 0, stream>>>(x_in, stats + 0);   // S0 = bn1 stats block 0

    for (int i = 0; i < 2; ++i) {
        const int* ip = (i == 0) ? ip1 : ip2;
        const float* asrc = (i == 0) ? x_in : xbuf;
        float* S_bn1 = stats + (i == 0 ? 0 : 2 * 2048);
        float* S_bn2 = stats + (i == 0 ? 1 * 2048 : 3 * 2048);
        const u16* wt_qkv = wtb + i * 49152;
        const u16* wt_proj = wtb + 98304 + i * 16384;
        const u16* wt_fc1 = wtb + 131072 + i * 65536;
        const u16* wt_fc2 = wtb + 262144 + i * 65536;

        bn_finalize<<<1, 128, 0, stream>>>(S_bn1, n1g + i * 128, n1b + i * 128, scsh);
        attn_fused<<<2048, 256, 0, stream>>>(asrc, xbuf, ip, scsh, wt_qkv, wt_proj, S_bn2);
        bn_finalize<<<1, 128, 0, stream>>>(S_bn2, n2g + i * 128, n2b + i * 128, scsh);
        mlp_fused<<<1024, 256, 0, stream>>>(xbuf, (i == 0) ? xbuf : out_x, scsh,
                                            wt_fc1, wt_fc2,
                                            (i == 0) ? (stats + 2 * 2048) : nullptr);
    }
}

// Round 9
// 548.379 us; speedup vs baseline: 1.5665x; 1.5665x over previous
//
#include <hip/hip_runtime.h>
#include <cstdint>
#include <cstddef>

typedef uint16_t u16;
typedef __bf16 bf16x8 __attribute__((ext_vector_type(8)));
typedef __bf16 bf16x4 __attribute__((ext_vector_type(4)));
typedef short s16x4 __attribute__((ext_vector_type(4)));
typedef float f32x4 __attribute__((ext_vector_type(4)));
typedef unsigned short us4 __attribute__((ext_vector_type(4)));

#define NTOK 131072          // B*N = 8*16384
#define CDIM 128
#define MFMA __builtin_amdgcn_mfma_f32_16x16x32_bf16

__device__ __forceinline__ u16 f2b(float f) {
    unsigned int x = __builtin_bit_cast(unsigned int, f);
    unsigned int r = (x + 0x7fffu + ((x >> 16) & 1u)) >> 16;
    return (u16)r;
}

__device__ __forceinline__ us4 pack_bn4(float4 v, const float* sc, const float* sh, int c) {
    us4 o;
    o.x = f2b(v.x * sc[c] + sh[c]);
    o.y = f2b(v.y * sc[c + 1] + sh[c + 1]);
    o.z = f2b(v.z * sc[c + 2] + sh[c + 2]);
    o.w = f2b(v.w * sc[c + 3] + sh[c + 3]);
    return o;
}

__device__ __forceinline__ s16x4 cvt4(f32x4 v) {
    bf16x4 b;
    b[0] = (__bf16)v[0]; b[1] = (__bf16)v[1];
    b[2] = (__bf16)v[2]; b[3] = (__bf16)v[3];
    return __builtin_bit_cast(s16x4, b);
}

// 16x16x16 bf16 MFMA (K=16): A/B = s16x4 (4 bf16), C = f32x4.
__device__ __forceinline__ f32x4 mfma16(s16x4 a, s16x4 b, f32x4 c) {
#if __has_builtin(__builtin_amdgcn_mfma_f32_16x16x16bf16_1k)
    return __builtin_amdgcn_mfma_f32_16x16x16bf16_1k(a, b, c, 0, 0, 0);
#else
    asm volatile("s_nop 3\n\tv_mfma_f32_16x16x16_bf16 %0, %1, %2, %0\n\ts_nop 7"
                 : "+v"(c) : "v"(a), "v"(b));
    return c;
#endif
}

__device__ __forceinline__ void gload16(const void* g, void* l) {
    __builtin_amdgcn_global_load_lds((const __attribute__((address_space(1))) void*)g,
                                     (__attribute__((address_space(3))) void*)l, 16, 0, 0);
}

// ---------------- initial BN stats on x_in (vectorized, 8-way spread atomics)
__global__ __launch_bounds__(256) void bn_init(const float* __restrict__ x,
                                               float* __restrict__ acc) {
    int tid = threadIdx.x;
    int c4 = tid & 31;
    int ro = tid >> 5;
    float4 s = {0.f, 0.f, 0.f, 0.f}, s2 = {0.f, 0.f, 0.f, 0.f};
    size_t base = ((size_t)blockIdx.x * 128 + ro) * 128 + c4 * 4;
#pragma unroll
    for (int it = 0; it < 16; ++it) {
        float4 v = *(const float4*)(x + base + (size_t)it * 1024);
        s.x += v.x; s.y += v.y; s.z += v.z; s.w += v.w;
        s2.x += v.x * v.x; s2.y += v.y * v.y; s2.z += v.z * v.z; s2.w += v.w * v.w;
    }
    __shared__ float4 a1[256], a2[256];
    a1[tid] = s; a2[tid] = s2;
    __syncthreads();
    if (tid < 128) {
        int col4 = tid >> 2, comp = tid & 3;
        float t1 = 0.f, t2 = 0.f;
#pragma unroll
        for (int r = 0; r < 8; ++r) {
            t1 += a1[r * 32 + col4][comp];
            t2 += a2[r * 32 + col4][comp];
        }
        float* st = acc + (blockIdx.x & 7) * 256;
        atomicAdd(st + tid, t1);
        atomicAdd(st + 128 + tid, t2);
    }
}

// ---------------- finalize: sum 8 copies, produce scale/shift
__global__ void bn_finalize(const float* __restrict__ acc, const float* __restrict__ g,
                            const float* __restrict__ b, float* __restrict__ scsh) {
    int c = threadIdx.x;  // 128 threads
    const float invn = 1.0f / (float)NTOK;
    float s = 0.f, q = 0.f;
#pragma unroll
    for (int k = 0; k < 8; ++k) {
        s += acc[k * 256 + c];
        q += acc[k * 256 + 128 + c];
    }
    float mean = s * invn;
    float var = q * invn - mean * mean;
    float sc = g[c] * rsqrtf(var + 1e-5f);
    scsh[c] = sc;
    scsh[128 + c] = b[c] - mean * sc;
}

// ---------------- weight transpose+convert: wt[n*K+k] = bf16(w[k*N+n])
__global__ __launch_bounds__(256) void wtrans(const float* __restrict__ w, u16* __restrict__ wt,
                                              int K, int N) {
    int t = blockIdx.x * 256 + threadIdx.x;
    if (t >= K * N) return;
    int n = t % N, k = t / N;
    wt[(size_t)n * K + k] = f2b(w[t]);
}

// ---------------- fused attention block: gather+BN1+QKV+attn+proj+resid+BN2stats
// One 64-token window per block; wave = head. QK^T/softmax/PV fully in registers.
__global__ __launch_bounds__(256, 3) void attn_fused(
    const float* __restrict__ xsrc, float* __restrict__ xdst,
    const int* __restrict__ ip, const float* __restrict__ scsh,
    const u16* __restrict__ wqt, const u16* __restrict__ wpt,
    float* __restrict__ stat)
{
    __shared__ u16 buf[64 * 136];      // [tok][136]: h (BN'd, bf16), later O
    __shared__ float sc[128], sh[128];
    __shared__ int ipl[64];

    int tid = threadIdx.x;
    int lane = tid & 63, wv = tid >> 6;
    int l15 = lane & 15, hi = lane >> 4;
    int b = blockIdx.x >> 8;

    if (tid < 128) { sc[tid] = scsh[tid]; sh[tid] = scsh[128 + tid]; }
    if (tid < 64) ipl[tid] = ip[blockIdx.x * 64 + tid];
    __syncthreads();

    // ---- stage h = BN1(x[ip rows]) -> buf rows (272B stride)
    int c4 = tid & 31;
#pragma unroll
    for (int p = 0; p < 8; ++p) {
        int row = p * 8 + (tid >> 5);
        int grow = (b << 14) + ipl[row];
        float4 v = *(const float4*)(xsrc + (size_t)grow * 128 + c4 * 4);
        us4 o = pack_bn4(v, sc, sh, c4 * 4);
        *(us4*)(buf + row * 136 + c4 * 4) = o;
    }
    __syncthreads();

    // ---- QKV GEMMs. Q',K' swapped: [d][tok]; V normal: [tok][dv]. head = wv.
    f32x4 aQ[2][4], aK[2][4], aV[4][2];
#pragma unroll
    for (int i = 0; i < 2; ++i)
#pragma unroll
        for (int j = 0; j < 4; ++j) { aQ[i][j] = (f32x4){0,0,0,0}; aK[i][j] = (f32x4){0,0,0,0}; }
#pragma unroll
    for (int i = 0; i < 4; ++i)
#pragma unroll
        for (int j = 0; j < 2; ++j) aV[i][j] = (f32x4){0,0,0,0};

#pragma unroll
    for (int ks = 0; ks < 4; ++ks) {
        bf16x8 hf[4];
#pragma unroll
        for (int t = 0; t < 4; ++t)
            hf[t] = *(const bf16x8*)(buf + (t * 16 + l15) * 136 + ks * 32 + hi * 8);
        bf16x8 qf[2], kf[2], vf[2];
#pragma unroll
        for (int md = 0; md < 2; ++md) {
            int rq = wv * 32 + md * 16 + l15;
            qf[md] = *(const bf16x8*)(wqt + (size_t)rq * 128 + ks * 32 + hi * 8);
            kf[md] = *(const bf16x8*)(wqt + (size_t)(128 + rq) * 128 + ks * 32 + hi * 8);
            vf[md] = *(const bf16x8*)(wqt + (size_t)(256 + rq) * 128 + ks * 32 + hi * 8);
        }
#pragma unroll
        for (int md = 0; md < 2; ++md)
#pragma unroll
            for (int nt = 0; nt < 4; ++nt) {
                aQ[md][nt] = MFMA(qf[md], hf[nt], aQ[md][nt], 0, 0, 0);
                aK[md][nt] = MFMA(kf[md], hf[nt], aK[md][nt], 0, 0, 0);
            }
#pragma unroll
        for (int mt = 0; mt < 4; ++mt)
#pragma unroll
            for (int nd = 0; nd < 2; ++nd)
                aV[mt][nd] = MFMA(hf[mt], vf[nd], aV[mt][nd], 0, 0, 0);
    }

    // ---- convert to bf16 fragments (scale folded into Q)
    const float SCALE = 0.17677669529663687f;  // 1/sqrt(32)
    s16x4 qc[2][4], kc[2][4], vc[4][2];
#pragma unroll
    for (int md = 0; md < 2; ++md)
#pragma unroll
        for (int nt = 0; nt < 4; ++nt) {
            qc[md][nt] = cvt4(aQ[md][nt] * SCALE);
            kc[md][nt] = cvt4(aK[md][nt]);
        }
#pragma unroll
    for (int mt = 0; mt < 4; ++mt)
#pragma unroll
        for (int nd = 0; nd < 2; ++nd)
            vc[mt][nd] = cvt4(aV[mt][nd]);

    // ---- S' = K·Q^T : [k_tok][q], lane holds q=l15 col, 16 k per (mt,hi)
    f32x4 s[4][4];
#pragma unroll
    for (int i = 0; i < 4; ++i)
#pragma unroll
        for (int j = 0; j < 4; ++j) s[i][j] = (f32x4){0,0,0,0};
#pragma unroll
    for (int kt = 0; kt < 2; ++kt)
#pragma unroll
        for (int mt = 0; mt < 4; ++mt)
#pragma unroll
            for (int nt = 0; nt < 4; ++nt)
                s[mt][nt] = mfma16(kc[kt][mt], qc[kt][nt], s[mt][nt]);

    // ---- softmax over k (in-lane 16 + shfl over hi groups)
    float inv[4];
#pragma unroll
    for (int nt = 0; nt < 4; ++nt) {
        float m = -1e30f;
#pragma unroll
        for (int mt = 0; mt < 4; ++mt)
#pragma unroll
            for (int r = 0; r < 4; ++r) m = fmaxf(m, s[mt][nt][r]);
        m = fmaxf(m, __shfl_xor(m, 16));
        m = fmaxf(m, __shfl_xor(m, 32));
        float sum = 0.f;
#pragma unroll
        for (int mt = 0; mt < 4; ++mt) {
            f32x4 e;
#pragma unroll
            for (int r = 0; r < 4; ++r) e[r] = __expf(s[mt][nt][r] - m);
            sum += e[0] + e[1] + e[2] + e[3];
            s[mt][nt] = e;
        }
        sum += __shfl_xor(sum, 16);
        sum += __shfl_xor(sum, 32);
        inv[nt] = 1.0f / sum;
    }
    s16x4 pc[4][4];
#pragma unroll
    for (int mt = 0; mt < 4; ++mt)
#pragma unroll
        for (int nt = 0; nt < 4; ++nt) pc[mt][nt] = cvt4(s[mt][nt]);

    // ---- O^T = V^T·P : [dv][q]
    f32x4 o[2][4];
#pragma unroll
    for (int i = 0; i < 2; ++i)
#pragma unroll
        for (int j = 0; j < 4; ++j) o[i][j] = (f32x4){0,0,0,0};
#pragma unroll
    for (int kt = 0; kt < 4; ++kt)
#pragma unroll
        for (int md = 0; md < 2; ++md)
#pragma unroll
            for (int nt = 0; nt < 4; ++nt)
                o[md][nt] = mfma16(vc[kt][md], pc[kt][nt], o[md][nt]);
#pragma unroll
    for (int md = 0; md < 2; ++md)
#pragma unroll
        for (int nt = 0; nt < 4; ++nt) o[md][nt] *= inv[nt];

    // ---- write O (bf16) to buf[tok][dv] (h is dead; all QKV reads done)
    __syncthreads();
#pragma unroll
    for (int md = 0; md < 2; ++md)
#pragma unroll
        for (int nt = 0; nt < 4; ++nt) {
            s16x4 w = cvt4(o[md][nt]);
            *(s16x4*)(buf + (nt * 16 + l15) * 136 + wv * 32 + md * 16 + hi * 4) = w;
        }
    __syncthreads();

    // ---- proj: out 64 x 32 per wave + residual + BN2 stats
    f32x4 p[4][2];
#pragma unroll
    for (int i = 0; i < 4; ++i)
#pragma unroll
        for (int j = 0; j < 2; ++j) p[i][j] = (f32x4){0,0,0,0};
#pragma unroll
    for (int ks = 0; ks < 4; ++ks) {
        bf16x8 af[4];
#pragma unroll
        for (int t = 0; t < 4; ++t)
            af[t] = *(const bf16x8*)(buf + (t * 16 + l15) * 136 + ks * 32 + hi * 8);
#pragma unroll
        for (int nt = 0; nt < 2; ++nt) {
            bf16x8 bf = *(const bf16x8*)(wpt + (size_t)(wv * 32 + nt * 16 + l15) * 128 + ks * 32 + hi * 8);
#pragma unroll
            for (int t = 0; t < 4; ++t)
                p[t][nt] = MFMA(af[t], bf, p[t][nt], 0, 0, 0);
        }
    }
    float cs[2] = {0.f, 0.f}, cq[2] = {0.f, 0.f};
#pragma unroll
    for (int t = 0; t < 4; ++t)
#pragma unroll
        for (int r = 0; r < 4; ++r) {
            int tok = t * 16 + hi * 4 + r;
            size_t grow = (size_t)((b << 14) + ipl[tok]) * 128;
#pragma unroll
            for (int nt = 0; nt < 2; ++nt) {
                int col = wv * 32 + nt * 16 + l15;
                float v = p[t][nt][r] + xsrc[grow + col];
                xdst[grow + col] = v;
                cs[nt] += v; cq[nt] += v * v;
            }
        }
#pragma unroll
    for (int nt = 0; nt < 2; ++nt) {
        cs[nt] += __shfl_xor(cs[nt], 16); cs[nt] += __shfl_xor(cs[nt], 32);
        cq[nt] += __shfl_xor(cq[nt], 16); cq[nt] += __shfl_xor(cq[nt], 32);
    }
    if (lane < 16) {
        float* st = stat + (blockIdx.x & 7) * 256;
#pragma unroll
        for (int nt = 0; nt < 2; ++nt) {
            int col = wv * 32 + nt * 16 + l15;
            atomicAdd(st + col, cs[nt]);
            atomicAdd(st + 128 + col, cq[nt]);
        }
    }
}

// ---------------- fused MLP: BN2+fc1+relu+fc2+resid (+next BN1 stats)
// Block = 8 waves / 256 tokens. Weights LDS-staged per 128-hidden chunk via
// global_load_lds (XOR-swizzled through pre-swizzled source addresses).
// fc1 swapped (C'[h][tok]); accumulator feeds fc2 mfma16 A-frag directly.
__global__ __launch_bounds__(512, 4) void mlp_fused(
    const float* __restrict__ xsrc, float* __restrict__ xdst,
    const float* __restrict__ scsh,
    const u16* __restrict__ w1t, const u16* __restrict__ w2t,
    float* __restrict__ stat)
{
    __shared__ u16 w1s[128 * 128];   // fc1 chunk [h][k], 256B rows, XOR-swizzled
    __shared__ u16 w2s[128 * 128];   // fc2 chunk [n][k], 256B rows, XOR-swizzled
    __shared__ float sc[128], sh[128];
    int tid = threadIdx.x, lane = tid & 63, wv = tid >> 6;   // 8 waves
    int l15 = lane & 15, hi = lane >> 4;
    int tok0 = blockIdx.x * 256 + wv * 32;
    if (tid < 128) { sc[tid] = scsh[tid]; sh[tid] = scsh[128 + tid]; }

    // ---- stage chunk 0 weights (overlaps h-load below)
    {
        int ch = 0;
#pragma unroll
        for (int j = 0; j < 4; ++j) {
            int base = (wv * 4 + j) * 1024;     // wave-uniform LDS byte base
            int f = base + lane * 16;           // this lane's flat byte
            int r = f >> 8, bd = f & 255;
            int bs = bd ^ ((r & 7) << 4);       // pre-swizzled source column
            gload16(w1t + (size_t)(ch * 128 + r) * 128 + (bs >> 1), (char*)w1s + base);
            gload16(w2t + (size_t)r * 512 + ch * 128 + (bs >> 1), (char*)w2s + base);
        }
    }
    __syncthreads();   // sc/sh ready (also drains stage-0, harmless)

    // ---- h B-frags straight from global with BN (lane = token l15), 2 subtiles
    bf16x8 hf[2][4];
#pragma unroll
    for (int mt = 0; mt < 2; ++mt)
#pragma unroll
        for (int ks = 0; ks < 4; ++ks) {
            const float* xr = xsrc + (size_t)(tok0 + mt * 16 + l15) * 128 + ks * 32 + hi * 8;
            float4 a = *(const float4*)xr;
            float4 bq = *(const float4*)(xr + 4);
            int c0 = ks * 32 + hi * 8;
            float4 s0 = *(const float4*)&sc[c0], s1 = *(const float4*)&sc[c0 + 4];
            float4 h0 = *(const float4*)&sh[c0], h1 = *(const float4*)&sh[c0 + 4];
            bf16x8 h;
            h[0] = (__bf16)(a.x * s0.x + h0.x); h[1] = (__bf16)(a.y * s0.y + h0.y);
            h[2] = (__bf16)(a.z * s0.z + h0.z); h[3] = (__bf16)(a.w * s0.w + h0.w);
            h[4] = (__bf16)(bq.x * s1.x + h1.x); h[5] = (__bf16)(bq.y * s1.y + h1.y);
            h[6] = (__bf16)(bq.z * s1.z + h1.z); h[7] = (__bf16)(bq.w * s1.w + h1.w);
            hf[mt][ks] = h;
        }

    f32x4 a2[8][2];
#pragma unroll
    for (int n = 0; n < 8; ++n) { a2[n][0] = (f32x4){0,0,0,0}; a2[n][1] = (f32x4){0,0,0,0}; }

    for (int ch = 0; ch < 4; ++ch) {
        __syncthreads();   // staging of chunk ch complete (vmcnt drained by compiler)

        // fc1: per 16-h tile, 4x K=32 MFMA from LDS; relu+cvt -> fc2 A-frag
        s16x4 pcv[8][2];
#pragma unroll
        for (int ht = 0; ht < 8; ++ht) {
            f32x4 a1[2] = {(f32x4){0,0,0,0}, (f32x4){0,0,0,0}};
#pragma unroll
            for (int ks = 0; ks < 4; ++ks) {
                int row = ht * 16 + l15;
                int cb = (ks * 64 + hi * 16) ^ ((row & 7) << 4);
                bf16x8 wf = *(const bf16x8*)((const char*)w1s + row * 256 + cb);
                a1[0] = MFMA(wf, hf[0][ks], a1[0], 0, 0, 0);
                a1[1] = MFMA(wf, hf[1][ks], a1[1], 0, 0, 0);
            }
#pragma unroll
            for (int mt = 0; mt < 2; ++mt) {
                f32x4 v = a1[mt];
#pragma unroll
                for (int r = 0; r < 4; ++r) v[r] = fmaxf(v[r], 0.f);
                pcv[ht][mt] = cvt4(v);
            }
        }
        // fc2: k-chunks of 16 via mfma16; B-frag from LDS (8B swizzled reads)
#pragma unroll
        for (int ht = 0; ht < 8; ++ht)
#pragma unroll
            for (int nt = 0; nt < 8; ++nt) {
                int row = nt * 16 + l15;
                int cb = (ht * 32 + hi * 8) ^ ((row & 7) << 4);
                s16x4 wb = *(const s16x4*)((const char*)w2s + row * 256 + cb);
                a2[nt][0] = mfma16(pcv[ht][0], wb, a2[nt][0]);
                a2[nt][1] = mfma16(pcv[ht][1], wb, a2[nt][1]);
            }

        if (ch < 3) {
            __syncthreads();   // all waves done reading chunk ch
            int nch = ch + 1;
#pragma unroll
            for (int j = 0; j < 4; ++j) {
                int base = (wv * 4 + j) * 1024;
                int f = base + lane * 16;
                int r = f >> 8, bd = f & 255;
                int bs = bd ^ ((r & 7) << 4);
                gload16(w1t + (size_t)(nch * 128 + r) * 128 + (bs >> 1), (char*)w1s + base);
                gload16(w2t + (size_t)r * 512 + nch * 128 + (bs >> 1), (char*)w2s + base);
            }
        }
    }

    // ---- epilogue: residual + write + (optional) next-BN1 stats
    float cs[8], cq[8];
#pragma unroll
    for (int n = 0; n < 8; ++n) { cs[n] = 0.f; cq[n] = 0.f; }
#pragma unroll
    for (int mt = 0; mt < 2; ++mt)
#pragma unroll
        for (int r = 0; r < 4; ++r) {
            size_t row = (size_t)(tok0 + mt * 16 + hi * 4 + r) * 128;
#pragma unroll
            for (int nt = 0; nt < 8; ++nt) {
                int col = nt * 16 + l15;
                float v = a2[nt][mt][r] + xsrc[row + col];
                xdst[row + col] = v;
                cs[nt] += v; cq[nt] += v * v;
            }
        }
    if (stat) {
#pragma unroll
        for (int nt = 0; nt < 8; ++nt) {
            cs[nt] += __shfl_xor(cs[nt], 16); cs[nt] += __shfl_xor(cs[nt], 32);
            cq[nt] += __shfl_xor(cq[nt], 16); cq[nt] += __shfl_xor(cq[nt], 32);
        }
        if (lane < 16) {
            float* st = stat + (blockIdx.x & 7) * 256;
#pragma unroll
            for (int nt = 0; nt < 8; ++nt) {
                int col = nt * 16 + l15;
                atomicAdd(st + col, cs[nt]);
                atomicAdd(st + 128 + col, cq[nt]);
            }
        }
    }
}

extern "C" void kernel_launch(void* const* d_in, const int* in_sizes, int n_in,
                              void* d_out, int out_size, void* d_ws, size_t ws_size,
                              hipStream_t stream) {
    const float* x_in = (const float*)d_in[0];
    const float* z_in = (const float*)d_in[1];
    const int* ip1 = (const int*)d_in[2];
    const int* ip2 = (const int*)d_in[3];
    const float* qkv_w = (const float*)d_in[4];
    const float* proj_w = (const float*)d_in[5];
    const float* fc1_w = (const float*)d_in[6];
    const float* fc2_w = (const float*)d_in[7];
    const float* n1g = (const float*)d_in[8];
    const float* n1b = (const float*)d_in[9];
    const float* n2g = (const float*)d_in[10];
    const float* n2b = (const float*)d_in[11];

    char* ws = (char*)d_ws;
    float* xbuf = (float*)(ws + 0);                 // 67,108,864 B
    u16* wtb = (u16*)(ws + 67108864);               // 786,432 B
    float* stats = (float*)(ws + 67895296);         // S0..S3: 4 x 2048 floats (8 copies each)
    float* scsh = stats + 4 * 2048;                 // 256 floats

    float* out_x = (float*)d_out;
    float* out_z = out_x + (size_t)NTOK * CDIM;

    hipMemsetAsync(stats, 0, 4 * 2048 * sizeof(float), stream);
    hipMemcpyAsync(out_z, z_in, (size_t)NTOK * 3 * sizeof(float),
                   hipMemcpyDeviceToDevice, stream);

    for (int i = 0; i < 2; ++i) {
        wtrans<<<(128 * 384 + 255) / 256, 256, 0, stream>>>(qkv_w + (size_t)i * 128 * 384,
                                                            wtb + i * 49152, 128, 384);
        wtrans<<<(128 * 128 + 255) / 256, 256, 0, stream>>>(proj_w + (size_t)i * 128 * 128,
                                                            wtb + 98304 + i * 16384, 128, 128);
        wtrans<<<(128 * 512 + 255) / 256, 256, 0, stream>>>(fc1_w + (size_t)i * 128 * 512,
                                                            wtb + 131072 + i * 65536, 128, 512);
        wtrans<<<(512 * 128 + 255) / 256, 256, 0, stream>>>(fc2_w + (size_t)i * 512 * 128,
                                                            wtb + 262144 + i * 65536, 512, 128);
    }

    bn_init<<<1024, 256, 0, stream>>>(x_in, stats + 0);   // S0 = bn1 stats block 0

    for (int i = 0; i < 2; ++i) {
        const int* ip = (i == 0) ? ip1 : ip2;
        const float* asrc = (i == 0) ? x_in : xbuf;
        float* S_bn1 = stats + (i == 0 ? 0 : 2 * 2048);
        float* S_bn2 = stats + (i == 0 ? 1 * 2048 : 3 * 2048);
        const u16* wt_qkv = wtb + i * 49152;
        const u16* wt_proj = wtb + 98304 + i * 16384;
        const u16* wt_fc1 = wtb + 131072 + i * 65536;
        const u16* wt_fc2 = wtb + 262144 + i * 65536;

        bn_finalize<<<1, 128, 0, stream>>>(S_bn1, n1g + i * 128, n1b + i * 128, scsh);
        attn_fused<<<2048, 256, 0, stream>>>(asrc, xbuf, ip, scsh, wt_qkv, wt_proj, S_bn2);
        bn_finalize<<<1, 128, 0, stream>>>(S_bn2, n2g + i * 128, n2b + i * 128, scsh);
        mlp_fused<<<512, 512, 0, stream>>>(xbuf, (i == 0) ? xbuf : out_x, scsh,
                                           wt_fc1, wt_fc2,
                                           (i == 0) ? (stats + 2 * 2048) : nullptr);
    }
}